// Round 3
// baseline (1811.675 us; speedup 1.0000x reference)
//
#include <hip/hip_runtime.h>
#include <hip/hip_bf16.h>

#define DD   64      // feature dim
#define NL   5       // layers
#define NT   37      // classes
#define LD   (NL*DD) // 320

// ---------------------------------------------------------------------------
// fp32 -> bf16 convert (initial h table)
__global__ void tobf16_kernel(const float* __restrict__ x, __hip_bfloat16* __restrict__ hb,
                              size_t n) {
    size_t i = (size_t)blockIdx.x * blockDim.x + threadIdx.x;
    if (i < n) hb[i] = __float2bfloat16(x[i]);
}

// ---------------------------------------------------------------------------
// CSR build: degree histogram
__global__ void deg_kernel(const int* __restrict__ dst, int* __restrict__ deg, int E) {
    int e = blockIdx.x * blockDim.x + threadIdx.x;
    if (e < E) atomicAdd(&deg[dst[e]], 1);
}

// Pass 1: per-1024-chunk sums (256 thr x 4 elems)
__global__ void chunksum_kernel(const int* __restrict__ deg, int* __restrict__ csum, int n) {
    __shared__ int sm[256];
    int tid = threadIdx.x;
    int base = blockIdx.x * 1024 + tid * 4;
    int s = 0;
#pragma unroll
    for (int j = 0; j < 4; ++j) s += (base + j < n) ? deg[base + j] : 0;
    sm[tid] = s;
    __syncthreads();
    for (int off = 128; off > 0; off >>= 1) {
        if (tid < off) sm[tid] += sm[tid + off];
        __syncthreads();
    }
    if (tid == 0) csum[blockIdx.x] = sm[0];
}

// Pass 2: single-block exclusive scan of chunk sums (nc <= 1024); writes total to *tot
__global__ void scansums_kernel(int* __restrict__ csum, int nc, int* __restrict__ tot) {
    __shared__ int sm[256];
    int tid = threadIdx.x;
    int base = tid * 4;
    int v[4]; int s = 0;
#pragma unroll
    for (int j = 0; j < 4; ++j) { v[j] = (base + j < nc) ? csum[base + j] : 0; s += v[j]; }
    sm[tid] = s;
    __syncthreads();
    for (int off = 1; off < 256; off <<= 1) {
        int t = (tid >= off) ? sm[tid - off] : 0;
        __syncthreads();
        sm[tid] += t;
        __syncthreads();
    }
    int p = sm[tid] - s;
#pragma unroll
    for (int j = 0; j < 4; ++j) { if (base + j < nc) csum[base + j] = p; p += v[j]; }
    if (tid == 255) *tot = p;
}

// Pass 3: scan within chunk + chunk offset -> rowptr, cursor
__global__ void chunkscan_kernel(const int* __restrict__ deg, const int* __restrict__ csum,
                                 int* __restrict__ rowptr, int* __restrict__ cursor, int n) {
    __shared__ int sm[256];
    int tid = threadIdx.x;
    int base = blockIdx.x * 1024 + tid * 4;
    int v[4]; int s = 0;
#pragma unroll
    for (int j = 0; j < 4; ++j) { v[j] = (base + j < n) ? deg[base + j] : 0; s += v[j]; }
    sm[tid] = s;
    __syncthreads();
    for (int off = 1; off < 256; off <<= 1) {
        int t = (tid >= off) ? sm[tid - off] : 0;
        __syncthreads();
        sm[tid] += t;
        __syncthreads();
    }
    int p = sm[tid] - s + csum[blockIdx.x];
#pragma unroll
    for (int j = 0; j < 4; ++j) {
        if (base + j < n) { rowptr[base + j] = p; cursor[base + j] = p; }
        p += v[j];
    }
}

// Fill CSR slots. PACKED: 32-B record per slot [ea0..ea6, src_as_int].
template<bool PACKED>
__global__ void fill_kernel(const int* __restrict__ dst, const int* __restrict__ src,
                            const float* __restrict__ ea, int* __restrict__ cursor,
                            float* __restrict__ erec, int* __restrict__ col,
                            int* __restrict__ srcv, int E) {
    int e = blockIdx.x * blockDim.x + threadIdx.x;
    if (e >= E) return;
    int p = atomicAdd(&cursor[dst[e]], 1);
    if (PACKED) {
        float* r = erec + (size_t)p * 8;
        const float* a = ea + (size_t)e * 7;
#pragma unroll
        for (int k = 0; k < 7; ++k) r[k] = a[k];
        ((int*)r)[7] = src[e];
    } else {
        col[p] = e;
        srcv[p] = src[e];
    }
}

// ---------------------------------------------------------------------------
// Fused layer: aggregation (+fused edge encoder) -> MLP -> pool partial.
// 512 threads = 8 waves = 8 nodes/block. lane = feature.
template<bool PACKED>
__global__ void layer_kernel(const __hip_bfloat16* __restrict__ hb_in,
                             const float* __restrict__ erec,
                             const int* __restrict__ col, const int* __restrict__ srcv,
                             const float* __restrict__ ea,
                             const int* __restrict__ rowptr,
                             const float* __restrict__ W_edge, const float* __restrict__ b_edge,
                             const float* __restrict__ eps, int layer,
                             const float* __restrict__ W, const float* __restrict__ bmlp,
                             const int* __restrict__ batch,
                             __hip_bfloat16* __restrict__ hb_out,
                             float* __restrict__ g_sum, int n) {
    __shared__ float wS[DD * DD];   // 16 KB, MLP weight, wS[l*64+j]
    int tid = threadIdx.x;
    {
        const float4* W4 = (const float4*)W;
        float4* wS4 = (float4*)wS;
        for (int i = tid; i < DD * DD / 4; i += 512) wS4[i] = W4[i];
    }
    __syncthreads();

    int wid = tid >> 6;
    int l = tid & 63;
    int v = blockIdx.x * 8 + wid;
    if (v >= n) return;   // wave-uniform

    float w[7];
#pragma unroll
    for (int k = 0; k < 7; ++k) w[k] = W_edge[k * DD + l];
    float be = b_edge[l];

    float acc = 0.f;
    int beg = rowptr[v], end = rowptr[v + 1];
    for (int p = beg; p < end; p += 4) {
        int m = end - p;
        float4 R0[4], R1[4];
        int   S[4];
        float HV[4];
        if (PACKED) {
#pragma unroll
            for (int j = 0; j < 4; ++j) {
                if (j < m) {
                    const float4* rp = (const float4*)(erec + (size_t)(p + j) * 8);
                    R0[j] = rp[0];
                    R1[j] = rp[1];
                }
            }
#pragma unroll
            for (int j = 0; j < 4; ++j) if (j < m) S[j] = __float_as_int(R1[j].w);
        } else {
            int EJ[4];
#pragma unroll
            for (int j = 0; j < 4; ++j) if (j < m) { EJ[j] = col[p + j]; S[j] = srcv[p + j]; }
#pragma unroll
            for (int j = 0; j < 4; ++j) {
                if (j < m) {
                    const float* a = ea + (size_t)EJ[j] * 7;
                    R0[j] = make_float4(a[0], a[1], a[2], a[3]);
                    R1[j] = make_float4(a[4], a[5], a[6], 0.f);
                }
            }
        }
#pragma unroll
        for (int j = 0; j < 4; ++j)
            if (j < m) HV[j] = __bfloat162float(hb_in[(size_t)S[j] * DD + l]);
#pragma unroll
        for (int j = 0; j < 4; ++j) {
            if (j < m) {
                float emb = be + R0[j].x * w[0] + R0[j].y * w[1] + R0[j].z * w[2]
                               + R0[j].w * w[3] + R1[j].x * w[4] + R1[j].y * w[5]
                               + R1[j].z * w[6];
                float t = HV[j] + emb;
                acc += (t > 0.f) ? t : 0.f;
            }
        }
    }
    float self = __bfloat162float(hb_in[(size_t)v * DD + l]);
    float u_val = (1.f + eps[layer]) * self + acc;   // u[v][lane]

    // MLP across the wave: h[j] = relu(bmlp[j] + sum_l u[l]*W[l][j]); lane==j
    float acc2 = bmlp[l];
#pragma unroll
    for (int k = 0; k < DD; ++k) {
        float ub = __shfl(u_val, k);
        acc2 += ub * wS[k * DD + l];
    }
    float h = (acc2 > 0.f) ? acc2 : 0.f;

    hb_out[(size_t)v * DD + l] = __float2bfloat16(h);
    int b = batch[v];
    atomicAdd(&g_sum[(size_t)b * LD + layer * DD + l], h);
}

// ---------------------------------------------------------------------------
// Per-graph node counts via binary search over SORTED batch.
__global__ void graph_cnt_kernel(const int* __restrict__ batch, int* __restrict__ cnt,
                                 int n, int G) {
    int g = blockIdx.x * blockDim.x + threadIdx.x;
    if (g >= G) return;
    int lo = 0, hi = n;
    while (lo < hi) { int mid = (lo + hi) >> 1; if (batch[mid] < g) lo = mid + 1; else hi = mid; }
    int lb0 = lo;
    lo = lb0; hi = n;
    while (lo < hi) { int mid = (lo + hi) >> 1; if (batch[mid] < g + 1) lo = mid + 1; else hi = mid; }
    cnt[g] = lo - lb0;
}

// Readout: out[g][t] = b_pred[t] + sum_k (g_sum[g][k]/max(cnt,1)) * W_pred[k][t]
__global__ void readout_kernel(const float* __restrict__ g_sum, const int* __restrict__ cnt,
                               const float* __restrict__ W_pred, const float* __restrict__ b_pred,
                               float* __restrict__ out, int G) {
    int id = blockIdx.x * blockDim.x + threadIdx.x;
    if (id >= G * NT) return;
    int g = id / NT, t = id % NT;
    float c = (float)cnt[g];
    if (c < 1.f) c = 1.f;
    float inv = 1.f / c;
    float acc = b_pred[t];
    const float* gs = g_sum + (size_t)g * LD;
    for (int k = 0; k < LD; ++k) acc += gs[k] * inv * W_pred[k * NT + t];
    out[id] = acc;
}

// ---------------------------------------------------------------------------
extern "C" void kernel_launch(void* const* d_in, const int* in_sizes, int n_in,
                              void* d_out, int out_size, void* d_ws, size_t ws_size,
                              hipStream_t stream) {
    const float* x       = (const float*)d_in[0];
    const int*   eidx    = (const int*)d_in[1];
    const float* ea      = (const float*)d_in[2];
    const int*   batch   = (const int*)d_in[3];
    const float* W_edge  = (const float*)d_in[4];
    const float* b_edge  = (const float*)d_in[5];
    const float* eps     = (const float*)d_in[6];
    const float* W_mlp   = (const float*)d_in[7];
    const float* b_mlp   = (const float*)d_in[8];
    const float* W_pred  = (const float*)d_in[9];
    const float* b_pred  = (const float*)d_in[10];
    float* out = (float*)d_out;

    const int N = in_sizes[3];          // 100000
    const int E = in_sizes[2] / 7;      // 1250000
    const int G = out_size / NT;        // 128
    const int* src = eidx;              // edge_index[0]
    const int* dst = eidx + E;          // edge_index[1]
    const int NC = (N + 1023) / 1024;   // scan chunks

    // workspace layout (keep 16-B alignment for each region)
    char* w0 = (char*)d_ws;
    char* w = w0;
    __hip_bfloat16* hb0 = (__hip_bfloat16*)w;  w += (size_t)N * DD * 2;
    __hip_bfloat16* hb1 = (__hip_bfloat16*)w;  w += (size_t)N * DD * 2;
    int*   deg    = (int*)w;                   w += (size_t)N * 4;
    int*   rowptr = (int*)w;                   w += (size_t)(N + 4) * 4;   // padded for alignment
    int*   cursor = (int*)w;                   w += (size_t)N * 4;
    int*   csum   = (int*)w;                   w += (size_t)1024 * 4;
    float* g_sum  = (float*)w;                 w += (size_t)G * LD * 4;
    int*   cnt    = (int*)w;                   w += ((size_t)G * 4 + 15) & ~(size_t)15;
    int*   col    = (int*)w;                   w += (size_t)E * 4;
    int*   srcv   = (int*)w;                   w += (size_t)E * 4;
    size_t used = (size_t)(w - w0);
    float* erec = nullptr;
    if (ws_size >= used + (size_t)E * 32) erec = (float*)w;   // packed records
    const bool packed = (erec != nullptr);

    hipMemsetAsync(deg, 0, (size_t)N * 4, stream);
    hipMemsetAsync(g_sum, 0, (size_t)G * LD * 4, stream);

    // initial bf16 h table
    {
        size_t nElem = (size_t)N * DD;
        tobf16_kernel<<<(unsigned)((nElem + 1023) / 1024), 1024, 0, stream>>>(x, hb0, nElem);
    }

    // CSR build
    deg_kernel<<<(E + 255) / 256, 256, 0, stream>>>(dst, deg, E);
    chunksum_kernel<<<NC, 256, 0, stream>>>(deg, csum, N);
    scansums_kernel<<<1, 256, 0, stream>>>(csum, NC, rowptr + N);
    chunkscan_kernel<<<NC, 256, 0, stream>>>(deg, csum, rowptr, cursor, N);
    if (packed)
        fill_kernel<true><<<(E + 255) / 256, 256, 0, stream>>>(dst, src, ea, cursor,
                                                               erec, col, srcv, E);
    else
        fill_kernel<false><<<(E + 255) / 256, 256, 0, stream>>>(dst, src, ea, cursor,
                                                                erec, col, srcv, E);

    graph_cnt_kernel<<<1, 128, 0, stream>>>(batch, cnt, N, G);

    __hip_bfloat16* hin = hb0;
    __hip_bfloat16* hout = hb1;
    int layerBlocks = (N + 7) / 8;
    for (int i = 0; i < NL; ++i) {
        if (packed)
            layer_kernel<true><<<layerBlocks, 512, 0, stream>>>(
                hin, erec, col, srcv, ea, rowptr, W_edge, b_edge, eps, i,
                W_mlp + (size_t)i * DD * DD, b_mlp + (size_t)i * DD, batch,
                hout, g_sum, N);
        else
            layer_kernel<false><<<layerBlocks, 512, 0, stream>>>(
                hin, erec, col, srcv, ea, rowptr, W_edge, b_edge, eps, i,
                W_mlp + (size_t)i * DD * DD, b_mlp + (size_t)i * DD, batch,
                hout, g_sum, N);
        __hip_bfloat16* t = hin; hin = hout; hout = t;
    }

    readout_kernel<<<(G * NT + 255) / 256, 256, 0, stream>>>(g_sum, cnt, W_pred, b_pred, out, G);
}